// Round 5
// baseline (162.311 us; speedup 1.0000x reference)
//
#include <hip/hip_runtime.h>

// Retrace loss: T=8192, K=2048, gamma=0.99.
// decay = cumprod(gamma*iw); S = reverse-cumsum(td*decay);
// retrace = S / max(decay,1e-10); loss = mean(smooth_l1(q, retrace)).
//
// Scan-first, adaptive apply (c = gamma*iw <= 0.99 => decay strictly
// decreasing; once the f32 global prefix D0 underflows to 0, retrace == 0
// exactly in both our and the reference's arithmetic, and Ssuf==0 follows
// from the scan construction):
//  kA  : per 16-row chunk, LDS-tiled (phase1 stream -> LDS, phase2 chain):
//        chunk product P, chunk sum Zl. 24KB LDS -> 6 blocks/CU (occupancy
//        was the R1-R4 limiter: rate ~ waves x loads-in-flight).
//  kS1/kS2/kS3: hierarchical chunk scan -> D0 (in P), Ssuf (in Zl).
//  kBz : streams sv + D0; loss terms where d0==0 (retrace==0 there).
//  kBr : recompute chain from inputs only where d0!=0 (~200 rows for
//        typical data; correct for any data).

#define GAMMA 0.99f

constexpr int T_ = 8192;
constexpr int K_ = 2048;
constexpr int N_ = T_ - 1;        // 8191
constexpr int L_ = 16;            // rows per chunk
constexpr int NCHUNK = 512;       // last chunk: 15 rows
constexpr int SL = 16;            // chunks per superchunk
constexpr int SUP = NCHUNK / SL;  // 32
constexpr long long NK = (long long)N_ * K_;
constexpr int CK = NCHUNK * K_;  // 1,048,576
constexpr int SK = SUP * K_;     // 65,536

typedef float f4 __attribute__((ext_vector_type(4)));
typedef unsigned short us4 __attribute__((ext_vector_type(4)));

__device__ __forceinline__ unsigned short f2bf(float f) {  // RTNE
  unsigned u = __float_as_uint(f);
  u += 0x7FFFu + ((u >> 16) & 1u);
  return (unsigned short)(u >> 16);
}
__device__ __forceinline__ float bf2f(unsigned short h) {
  return __uint_as_float(((unsigned)h) << 16);
}

__device__ __forceinline__ void block_reduce_add(float l, double* acc) {
  for (int off = 32; off > 0; off >>= 1) l += __shfl_down(l, off);
  __shared__ float wsum[4];
  const int lane = threadIdx.x & 63, wid = threadIdx.x >> 6;
  if (lane == 0) wsum[wid] = l;
  __syncthreads();
  if (threadIdx.x == 0)
    atomicAdd(acc, (double)(wsum[0] + wsum[1] + wsum[2] + wsum[3]));
}

// ---------------------------------------------------------------- kA
// Tile: 16 rows x 256 cols. Grid (K/256, NCHUNK).
__global__ __launch_bounds__(256, 6) void kA(
    const float* __restrict__ tsv, const float* __restrict__ tev,
    const float* __restrict__ r, const float* __restrict__ ologp,
    const float* __restrict__ tlogp, float* __restrict__ P,
    float* __restrict__ Zl, double* __restrict__ acc) {
  __shared__ float csh[L_][256];            // 16 KB f32 c (exact chain)
  __shared__ unsigned short tdsh[L_][256];  // 8 KB bf16 td
  const int tid = threadIdx.x;
  const int lane = tid & 63;
  const int wid = tid >> 6;
  const int c0 = blockIdx.x * 256;
  const int chunk = blockIdx.y;
  const int i0 = chunk * L_;
  const int col = c0 + lane * 4;

  // phase 1: wave w handles rows w, w+4, w+8, w+12 (depth-1 pipeline)
  f4 lwA, aA, vA, rrA;
  float oA;
  auto issue = [&](int s, f4& lw, f4& a, f4& v, f4& rr, float& o) {
    int i = i0 + s;
    if (i >= N_) i = N_ - 1;  // clamp; masked in phase 2
    const size_t b1 = (size_t)(i + 1) * K_ + col;
    const size_t b0 = (size_t)i * K_ + col;
    lw = *(const f4*)(tlogp + b1);
    a = *(const f4*)(tsv + b1);
    v = *(const f4*)(tev + b1);
    rr = *(const f4*)(r + b0);
    o = ologp[i + 1];
  };
  issue(wid, lwA, aA, vA, rrA, oA);
#pragma unroll
  for (int s0 = 0; s0 < L_; s0 += 4) {
    const int s = s0 + wid;
    f4 lwB, aB, vB, rrB;
    float oB;
    if (s0 + 4 < L_) issue(s + 4, lwB, aB, vB, rrB, oB);
    __builtin_amdgcn_sched_barrier(0);  // loads for next batch stay early
    f4 iw, c, td;
#pragma unroll
    for (int x = 0; x < 4; ++x) iw[x] = __expf(fminf(lwA[x] - oA, 0.f));
#pragma unroll
    for (int x = 0; x < 4; ++x) c[x] = GAMMA * iw[x];
#pragma unroll
    for (int x = 0; x < 4; ++x)
      td[x] = fmaf(GAMMA, fmaf(-iw[x], aA[x], vA[x]), rrA[x]);
    *(f4*)&csh[s][lane * 4] = c;
    us4 t4;
#pragma unroll
    for (int x = 0; x < 4; ++x) t4[x] = f2bf(td[x]);
    *(us4*)&tdsh[s][lane * 4] = t4;
    if (s0 + 4 < L_) {
      lwA = lwB;
      aA = aB;
      vA = vB;
      rrA = rrB;
      oA = oB;
    }
  }
  __syncthreads();

  // phase 2: per-column f32 chain (16 rows)
  const int kcol = c0 + tid;
  const int nrow = min(L_, N_ - i0);
  float p = 1.f, zl = 0.f;
#pragma unroll
  for (int s = 0; s < L_; ++s) {
    if (s < nrow) {
      p *= csh[s][tid];
      zl = fmaf(bf2f(tdsh[s][tid]), p, zl);
    }
  }
  P[(size_t)chunk * K_ + kcol] = p;
  Zl[(size_t)chunk * K_ + kcol] = zl;
  if (blockIdx.x == 0 && blockIdx.y == 0 && tid == 0) *acc = 0.0;
}

// ---------------------------------------------------------------- kS1
__global__ __launch_bounds__(256) void kS1(const float* __restrict__ PD0,
                                           const float* __restrict__ ZS,
                                           float* __restrict__ SP,
                                           float* __restrict__ SZ) {
  const int g = blockIdx.x * 256 + threadIdx.x;  // 0..K*SUP-1
  const int k = g & (K_ - 1);
  const int s = g >> 11;  // /K_
  float sp = 1.f, sz = 0.f;
#pragma unroll
  for (int c = 0; c < SL; ++c) {
    const size_t idx = (size_t)(s * SL + c) * K_ + k;
    float pv = PD0[idx];
    float zv = ZS[idx];
    sz = fmaf(sp, zv, sz);
    sp *= pv;
  }
  SP[(size_t)s * K_ + k] = sp;
  SZ[(size_t)s * K_ + k] = sz;
}

// ---------------------------------------------------------------- kS2
__global__ __launch_bounds__(256) void kS2(const float* __restrict__ SP,
                                           const float* __restrict__ SZ,
                                           float* __restrict__ SD0,
                                           float* __restrict__ SSuf) {
  const int k = blockIdx.x * 256 + threadIdx.x;  // 0..K-1
  float d = 1.f;
  float sd[SUP];
#pragma unroll
  for (int s = 0; s < SUP; ++s) {
    sd[s] = d;
    SD0[(size_t)s * K_ + k] = d;
    d *= SP[(size_t)s * K_ + k];
  }
  float ss = 0.f;
#pragma unroll
  for (int s = SUP - 1; s >= 0; --s) {
    SSuf[(size_t)s * K_ + k] = ss;
    ss = fmaf(sd[s], SZ[(size_t)s * K_ + k], ss);
  }
}

// ---------------------------------------------------------------- kS3
// In-place: PD0: P -> D0 ; ZS: Zl -> Ssuf (same-thread read-then-write).
__global__ __launch_bounds__(256) void kS3(float* __restrict__ PD0,
                                           float* __restrict__ ZS,
                                           const float* __restrict__ SD0,
                                           const float* __restrict__ SSuf) {
  const int g = blockIdx.x * 256 + threadIdx.x;
  const int k = g & (K_ - 1);
  const int s = g >> 11;
  float d = SD0[(size_t)s * K_ + k];
  float darr[SL];
#pragma unroll
  for (int c = 0; c < SL; ++c) {
    const size_t idx = (size_t)(s * SL + c) * K_ + k;
    float pv = PD0[idx];
    darr[c] = d;
    PD0[idx] = d;  // D0_c
    d *= pv;
  }
  float ss = SSuf[(size_t)s * K_ + k];
#pragma unroll
  for (int c = SL - 1; c >= 0; --c) {
    const size_t idx = (size_t)(s * SL + c) * K_ + k;
    float zv = ZS[idx];
    ZS[idx] = ss;  // Ssuf_c (excludes own chunk)
    ss = fmaf(darr[c], zv, ss);
  }
}

// ---------------------------------------------------------------- kBz
// Zero-decay path: where D0[chunk][k]==0, retrace==0 -> loss=sl1(sv,0).
__global__ __launch_bounds__(256) void kBz(const float* __restrict__ sv,
                                           const float* __restrict__ D0,
                                           double* __restrict__ acc) {
  const long long nvec = NK / 4;
  float loss = 0.f;
  for (long long v = (long long)blockIdx.x * 256 + threadIdx.x; v < nvec;
       v += (long long)gridDim.x * 256) {
    const long long e = v * 4;
    const int i = (int)(e >> 11);  // row (K=2048)
    const int k = (int)(e & (K_ - 1));
    f4 q4 = *(const f4*)(sv + e);
    f4 d4 = *(const f4*)(D0 + (size_t)(i >> 4) * K_ + k);
#pragma unroll
    for (int x = 0; x < 4; ++x) {
      if (d4[x] == 0.f) {
        float ad = fabsf(q4[x]);
        loss += (ad < 1.f) ? 0.5f * ad * ad : ad - 0.5f;
      }
    }
  }
  block_reduce_add(loss, acc);
}

// ---------------------------------------------------------------- kBr
// Recompute path: (chunk,col) with d0 != 0. Rare for typical data;
// correct (just slower) for any data.
__global__ __launch_bounds__(256) void kBr(
    const float* __restrict__ sv, const float* __restrict__ tsv,
    const float* __restrict__ tev, const float* __restrict__ r,
    const float* __restrict__ ologp, const float* __restrict__ tlogp,
    const float* __restrict__ D0, const float* __restrict__ Ssuf,
    double* __restrict__ acc) {
  const int chunk = blockIdx.x;
  const int k = blockIdx.y * 256 + threadIdx.x;
  const int i0 = chunk * L_;
  const int nrow = min(L_, N_ - i0);
  const float d0 = D0[(size_t)chunk * K_ + k];
  float loss = 0.f;
  if (__any(d0 != 0.f)) {
    if (d0 != 0.f) {
      float ld[L_], td[L_];
      float p = 1.f;
#pragma unroll
      for (int s = 0; s < L_; ++s) {
        if (s < nrow) {
          const int i = i0 + s;
          const size_t b1 = (size_t)(i + 1) * K_ + k;
          float iw = __expf(fminf(tlogp[b1] - ologp[i + 1], 0.f));
          p *= GAMMA * iw;
          ld[s] = p;
          // round td through bf16 to match kA's Zl construction
          td[s] = bf2f(f2bf(
              fmaf(GAMMA, fmaf(-iw, tsv[b1], tev[b1]), r[(size_t)i * K_ + k])));
        }
      }
      const float ssuf = Ssuf[(size_t)chunk * K_ + k];
      float slocal = 0.f;
#pragma unroll
      for (int s = L_ - 1; s >= 0; --s) {
        if (s < nrow) {
          slocal = fmaf(td[s], ld[s], slocal);
          float S = fmaf(d0, slocal, ssuf);
          float retrace = S / fmaxf(d0 * ld[s], 1e-10f);
          float dd = sv[(size_t)(i0 + s) * K_ + k] - retrace;
          float ad = fabsf(dd);
          loss += (ad < 1.f) ? 0.5f * dd * dd : ad - 0.5f;
        }
      }
    }
  }
  block_reduce_add(loss, acc);
}

// ---------------------------------------------------------------- k4
__global__ void k4(const double* __restrict__ acc, float* __restrict__ out) {
  out[0] = (float)(*acc * (1.0 / ((double)N_ * (double)K_)));
}

extern "C" void kernel_launch(void* const* d_in, const int* in_sizes, int n_in,
                              void* d_out, int out_size, void* d_ws,
                              size_t ws_size, hipStream_t stream) {
  const float* sv = (const float*)d_in[0];
  const float* tsv = (const float*)d_in[1];
  const float* tev = (const float*)d_in[2];
  const float* r = (const float*)d_in[3];
  const float* ologp = (const float*)d_in[4];
  const float* tlogp = (const float*)d_in[5];

  float* f = (float*)d_ws;  // needs ~9.4 MB (harness gives >=75 MB)
  float* P = f;             // CK floats: P, then D0 in place
  float* Zl = f + CK;       // CK floats: Zl, then Ssuf in place
  float* SP = f + 2 * (size_t)CK;
  float* SZ = SP + SK;
  float* SD0 = SZ + SK;
  float* SSuf = SD0 + SK;
  double* acc = (double*)(SSuf + SK);

  kA<<<dim3(K_ / 256, NCHUNK), 256, 0, stream>>>(tsv, tev, r, ologp, tlogp, P,
                                                 Zl, acc);
  kS1<<<SK / 256, 256, 0, stream>>>(P, Zl, SP, SZ);
  kS2<<<K_ / 256, 256, 0, stream>>>(SP, SZ, SD0, SSuf);
  kS3<<<SK / 256, 256, 0, stream>>>(P, Zl, SD0, SSuf);  // P=D0, Zl=Ssuf now
  kBz<<<2048, 256, 0, stream>>>(sv, P, acc);
  kBr<<<dim3(NCHUNK, K_ / 256), 256, 0, stream>>>(sv, tsv, tev, r, ologp,
                                                  tlogp, P, Zl, acc);
  k4<<<1, 1, 0, stream>>>(acc, (float*)d_out);
}

// Round 6
// 52.101 us; speedup vs baseline: 3.1153x; 3.1153x over previous
//
#include <hip/hip_runtime.h>

// Retrace loss: T=8192, K=2048, gamma=0.99.
// decay = cumprod(gamma*iw); S = reverse-cumsum(td*decay);
// retrace = S / max(decay,1e-10); loss = mean(smooth_l1(q, retrace)).
//
// Key fact: c = gamma*iw <= 0.99, E[ln c] ~= -0.57, so the f32 decay
// underflows to EXACT 0 within ~170 rows for every column (at row 512 the
// log-decay is -294 +- ~18 sigma). Once decay==0 (f32), S==0 and
// retrace==0 exactly in both our and the reference's f32 arithmetic
// (validated absmax 0.0 in rounds 1-5). So:
//   kPre  : exact chunked scan for rows [0,512) only (R4-proven bf16 pk).
//   kScan : chunk prefix/suffix + per-column alive flag (512-row product
//           != 0) + nAlive count.
//   kApply: one fused kernel, roles by blockIdx:
//           A: prefix apply (pk + sv + D0/Ssuf, smooth-L1);
//           B: tail rows [512,8191): loss=sl1(sv,0) for dead columns
//              (only sv is read!);
//           C: per-column exact serial fallback for alive columns
//              (correctness for arbitrary data; no-op here).
//   k4    : mean.
// Demand: ~424 MB -> ~90 MB (L3-resident across replays).
// R1-R5 lesson: this 4-stream row-strided read pattern caps at ~3 TB/s
// demand regardless of occupancy/vectorization -> cut bytes, not latency.

#define GAMMA 0.99f

constexpr int T_ = 8192;
constexpr int K_ = 2048;
constexpr int N_ = T_ - 1;           // 8191
constexpr int MROWS = 512;           // exact-prefix length
constexpr int L_ = 16;               // rows per chunk
constexpr int MCH = MROWS / L_;      // 32 chunks
constexpr int NBPRE = MCH * (K_ / 256);  // 256 role-A blocks
constexpr int NBTAIL = 2048;             // role-B blocks
constexpr long long TAILF4 = (long long)(N_ - MROWS) * K_ / 4;  // 3,931,648

typedef float f4 __attribute__((ext_vector_type(4)));
typedef unsigned short us4 __attribute__((ext_vector_type(4)));

__device__ __forceinline__ unsigned short f2bf(float f) {  // RTNE
  unsigned u = __float_as_uint(f);
  u += 0x7FFFu + ((u >> 16) & 1u);
  return (unsigned short)(u >> 16);
}
__device__ __forceinline__ float bf2f(unsigned short h) {
  return __uint_as_float(((unsigned)h) << 16);
}
__device__ __forceinline__ float bfhi(unsigned q) {  // y in hi16
  return __uint_as_float(q & 0xFFFF0000u);
}
__device__ __forceinline__ float bflo(unsigned q) {  // ld in lo16
  return __uint_as_float(q << 16);
}
__device__ __forceinline__ float sl1(float dd) {
  float ad = fabsf(dd);
  return (ad < 1.f) ? 0.5f * dd * dd : ad - 0.5f;
}
__device__ __forceinline__ void block_reduce_add(float l, double* acc) {
  for (int off = 32; off > 0; off >>= 1) l += __shfl_down(l, off);
  __shared__ float wsum[4];
  const int lane = threadIdx.x & 63, wid = threadIdx.x >> 6;
  if (lane == 0) wsum[wid] = l;
  __syncthreads();
  if (threadIdx.x == 0)
    atomicAdd(acc, (double)(wsum[0] + wsum[1] + wsum[2] + wsum[3]));
}

// ---------------------------------------------------------------- kPre
// Rows [0,512): 16x256 LDS tile; phase1 stream->LDS, phase2 column chain.
// Writes packed bf16 (y|ld) per element + per-chunk P, Zl.
__global__ __launch_bounds__(256) void kPre(
    const float* __restrict__ tsv, const float* __restrict__ tev,
    const float* __restrict__ r, const float* __restrict__ ologp,
    const float* __restrict__ tlogp, unsigned* __restrict__ pkPre,
    float* __restrict__ P, float* __restrict__ Zl,
    unsigned* __restrict__ flagbits, unsigned* __restrict__ nAlive,
    double* __restrict__ acc) {
  __shared__ float csh[L_][256];            // f32 c (exact chain)
  __shared__ unsigned short tdsh[L_][256];  // bf16 td
  const int tid = threadIdx.x;
  const int lane = tid & 63;
  const int wid = tid >> 6;
  const int c0 = blockIdx.x * 256;
  const int chunk = blockIdx.y;
  const int i0 = chunk * L_;
  const int col = c0 + lane * 4;

  // phase 1: wave w handles rows w, w+4, w+8, w+12 (depth-1 pipeline)
  f4 lwA, aA, vA, rrA;
  float oA;
  auto issue = [&](int s, f4& lw, f4& a, f4& v, f4& rr, float& o) {
    const int i = i0 + s;
    const size_t b1 = (size_t)(i + 1) * K_ + col;
    const size_t b0 = (size_t)i * K_ + col;
    lw = *(const f4*)(tlogp + b1);
    a = *(const f4*)(tsv + b1);
    v = *(const f4*)(tev + b1);
    rr = *(const f4*)(r + b0);
    o = ologp[i + 1];
  };
  issue(wid, lwA, aA, vA, rrA, oA);
#pragma unroll
  for (int s0 = 0; s0 < L_; s0 += 4) {
    const int s = s0 + wid;
    f4 lwB, aB, vB, rrB;
    float oB;
    if (s0 + 4 < L_) issue(s + 4, lwB, aB, vB, rrB, oB);
    __builtin_amdgcn_sched_barrier(0);
    f4 iw, c, td;
#pragma unroll
    for (int x = 0; x < 4; ++x) iw[x] = __expf(fminf(lwA[x] - oA, 0.f));
#pragma unroll
    for (int x = 0; x < 4; ++x) c[x] = GAMMA * iw[x];
#pragma unroll
    for (int x = 0; x < 4; ++x)
      td[x] = fmaf(GAMMA, fmaf(-iw[x], aA[x], vA[x]), rrA[x]);
    *(f4*)&csh[s][lane * 4] = c;
    us4 t4;
#pragma unroll
    for (int x = 0; x < 4; ++x) t4[x] = f2bf(td[x]);
    *(us4*)&tdsh[s][lane * 4] = t4;
    if (s0 + 4 < L_) {
      lwA = lwB;
      aA = aB;
      vA = vB;
      rrA = rrB;
      oA = oB;
    }
  }
  __syncthreads();

  // phase 2: per-column f32 chain, store packed y|ld
  const int kcol = c0 + tid;
  float p = 1.f, zl = 0.f;
#pragma unroll
  for (int s = 0; s < L_; ++s) {
    p *= csh[s][tid];
    float y = bf2f(tdsh[s][tid]) * p;
    zl += y;
    pkPre[(size_t)(i0 + s) * K_ + kcol] = ((unsigned)f2bf(y) << 16) | f2bf(p);
  }
  P[(size_t)chunk * K_ + kcol] = p;
  Zl[(size_t)chunk * K_ + kcol] = zl;

  if (blockIdx.x == 0 && blockIdx.y == 0) {  // init for this launch
    if (tid < 64) flagbits[tid] = 0u;
    if (tid == 64) *nAlive = 0u;
    if (tid == 65) *acc = 0.0;
  }
}

// ---------------------------------------------------------------- kScan
// Per column: exclusive chunk prefix product D0, suffix sum Ssuf, alive
// flag = (product over all 512 rows != 0).
__global__ __launch_bounds__(256) void kScan(
    const float* __restrict__ P, const float* __restrict__ Zl,
    float* __restrict__ D0, float* __restrict__ Ssuf,
    unsigned* __restrict__ flagbits, unsigned* __restrict__ nAlive) {
  const int k = blockIdx.x * 256 + threadIdx.x;  // 0..K-1
  float d = 1.f;
  float sd[MCH];
#pragma unroll
  for (int c = 0; c < MCH; ++c) {
    sd[c] = d;
    D0[(size_t)c * K_ + k] = d;
    d *= P[(size_t)c * K_ + k];
  }
  if (d != 0.f) {  // alive: full-prefix decay survived (never, typically)
    atomicOr(&flagbits[k >> 5], 1u << (k & 31));
    atomicAdd(nAlive, 1u);
  }
  float ss = 0.f;
#pragma unroll
  for (int c = MCH - 1; c >= 0; --c) {
    Ssuf[(size_t)c * K_ + k] = ss;
    ss = fmaf(sd[c], Zl[(size_t)c * K_ + k], ss);
  }
}

// ---------------------------------------------------------------- kApply
// Role A (bid<NBPRE): prefix apply. Role B: tail sl1(sv,0) for dead cols.
// Role C: exact serial fallback per alive column.
__global__ __launch_bounds__(256) void kApply(
    const float* __restrict__ sv, const float* __restrict__ tsv,
    const float* __restrict__ tev, const float* __restrict__ r,
    const float* __restrict__ ologp, const float* __restrict__ tlogp,
    const unsigned* __restrict__ pkPre, const float* __restrict__ D0,
    const float* __restrict__ Ssuf, const unsigned* __restrict__ flagbits,
    const unsigned* __restrict__ nAlive, unsigned* __restrict__ pkFull,
    double* __restrict__ acc) {
  const int bid = blockIdx.x;
  const int tid = threadIdx.x;

  if (bid < NBPRE) {  // ---- role A: prefix rows [0,512)
    const int chunk = bid >> 3;
    const int kcol = (bid & 7) * 256 + tid;
    const int i0 = chunk * L_;
    float loss = 0.f;
    const bool alive = (flagbits[kcol >> 5] >> (kcol & 31)) & 1u;
    if (!alive) {
      const float d0 = D0[(size_t)chunk * K_ + kcol];
      const float ssuf = Ssuf[(size_t)chunk * K_ + kcol];
      float slocal = 0.f;
#pragma unroll
      for (int s = L_ - 1; s >= 0; --s) {
        const size_t b0 = (size_t)(i0 + s) * K_ + kcol;
        unsigned q = pkPre[b0];
        slocal += bfhi(q);
        float S = fmaf(d0, slocal, ssuf);
        float retrace = S / fmaxf(d0 * bflo(q), 1e-10f);
        loss += sl1(sv[b0] - retrace);
      }
    }
    block_reduce_add(loss, acc);
  } else if (bid < NBPRE + NBTAIL) {  // ---- role B: tail rows [512,8191)
    __shared__ unsigned fb[64];
    if (tid < 64) fb[tid] = flagbits[tid];
    __syncthreads();
    const unsigned nA = *nAlive;
    const long long base = (long long)MROWS * K_ / 4;  // f4 offset
    const int rb = bid - NBPRE;
    float loss = 0.f;
    if (nA == 0) {  // fast path: every column dead
      for (long long v = (long long)rb * 256 + tid; v < TAILF4;
           v += (long long)NBTAIL * 256) {
        f4 q = ((const f4*)sv)[base + v];
#pragma unroll
        for (int x = 0; x < 4; ++x) loss += sl1(q[x]);
      }
    } else {
      for (long long v = (long long)rb * 256 + tid; v < TAILF4;
           v += (long long)NBTAIL * 256) {
        f4 q = ((const f4*)sv)[base + v];
        const int k0 = (int)((v * 4) & (K_ - 1));
#pragma unroll
        for (int x = 0; x < 4; ++x) {
          const int k = k0 + x;
          if (!((fb[k >> 5] >> (k & 31)) & 1u)) loss += sl1(q[x]);
        }
      }
    }
    block_reduce_add(loss, acc);
  } else {  // ---- role C: exact fallback for alive columns (rare/never)
    const int col = bid - NBPRE - NBTAIL;
    if (!((flagbits[col >> 5] >> (col & 31)) & 1u)) return;
    if (tid != 0) return;
    unsigned* mycol = pkFull + (size_t)col * 8192;
    float p = 1.f;
    for (int i = 0; i < N_; ++i) {  // forward: exact sequential decay
      const size_t b1 = (size_t)(i + 1) * K_ + col;
      float iw = __expf(fminf(tlogp[b1] - ologp[i + 1], 0.f));
      p *= GAMMA * iw;
      float td =
          fmaf(GAMMA, fmaf(-iw, tsv[b1], tev[b1]), r[(size_t)i * K_ + col]);
      mycol[i] = ((unsigned)f2bf(td * p) << 16) | f2bf(p);
    }
    float slocal = 0.f, loss = 0.f;
    for (int i = N_ - 1; i >= 0; --i) {  // backward: S and loss
      unsigned q = mycol[i];
      slocal += bfhi(q);
      float retrace = slocal / fmaxf(bflo(q), 1e-10f);
      loss += sl1(sv[(size_t)i * K_ + col] - retrace);
    }
    atomicAdd(acc, (double)loss);
  }
}

// ---------------------------------------------------------------- k4
__global__ void k4(const double* __restrict__ acc, float* __restrict__ out) {
  out[0] = (float)(*acc * (1.0 / ((double)N_ * (double)K_)));
}

extern "C" void kernel_launch(void* const* d_in, const int* in_sizes, int n_in,
                              void* d_out, int out_size, void* d_ws,
                              size_t ws_size, hipStream_t stream) {
  const float* sv = (const float*)d_in[0];
  const float* tsv = (const float*)d_in[1];
  const float* tev = (const float*)d_in[2];
  const float* r = (const float*)d_in[3];
  const float* ologp = (const float*)d_in[4];
  const float* tlogp = (const float*)d_in[5];

  // ws layout (needs ~72.5 MB; harness provides >=75.5 MB, proven R2-R5):
  char* w = (char*)d_ws;
  unsigned* pkPre = (unsigned*)w;                   // 512*2048*4 = 4 MB
  w += (size_t)MROWS * K_ * 4;
  float* P = (float*)w;                             // 32*2048*4 = 256 KB
  w += (size_t)MCH * K_ * 4;
  float* Zl = (float*)w;
  w += (size_t)MCH * K_ * 4;
  float* D0 = (float*)w;
  w += (size_t)MCH * K_ * 4;
  float* Ssuf = (float*)w;
  w += (size_t)MCH * K_ * 4;
  unsigned* flagbits = (unsigned*)w;                // 64 words
  w += 256;
  unsigned* nAlive = (unsigned*)w;
  w += 256;
  double* acc = (double*)w;
  w += 256;
  unsigned* pkFull = (unsigned*)w;                  // 2048*8192*4 = 67 MB

  kPre<<<dim3(K_ / 256, MCH), 256, 0, stream>>>(tsv, tev, r, ologp, tlogp,
                                                pkPre, P, Zl, flagbits, nAlive,
                                                acc);
  kScan<<<K_ / 256, 256, 0, stream>>>(P, Zl, D0, Ssuf, flagbits, nAlive);
  kApply<<<NBPRE + NBTAIL + K_, 256, 0, stream>>>(
      sv, tsv, tev, r, ologp, tlogp, pkPre, D0, Ssuf, flagbits, nAlive, pkFull,
      acc);
  k4<<<1, 1, 0, stream>>>(acc, (float*)d_out);
}